// Round 2
// baseline (29.849 us; speedup 1.0000x reference)
//
#include <hip/hip_runtime.h>

#define NB   16
#define NN   256
#define INF  128
#define OUTF 64
#define NHH  12
#define NEGV -9000000000000000.0f
#define L2E  1.44269504088896340736f

// ---------------- kernel 1: h = x@W^T, e_src = h@A1^T, e_dst = h@A2^T ----
__global__ __launch_bounds__(256) void k1_proj(
    const float* __restrict__ x, const float* __restrict__ W,
    const float* __restrict__ A,
    float* __restrict__ hout, float* __restrict__ esrc, float* __restrict__ edst)
{
    __shared__ float wl[64 * 132];   // W padded pitch 132 (bank-conflict-free float4)
    __shared__ float xs[16 * 128];
    __shared__ float hs[16 * 64];
    const int t = threadIdx.x;
    const int row0 = blockIdx.x * 16;   // flat row over (B*N)

#pragma unroll
    for (int i = 0; i < 32; ++i) {
        int idx = t + 256 * i;          // 0..8191
        wl[(idx >> 7) * 132 + (idx & 127)] = W[idx];
    }
#pragma unroll
    for (int i = 0; i < 8; ++i) {
        int idx = t + 256 * i;          // 0..2047
        xs[idx] = x[row0 * INF + idx];
    }
    __syncthreads();

    const int o = t & 63;               // output feature
    const int w = t >> 6;               // wave id: rows w*4..w*4+3
    float acc[4] = {0.f, 0.f, 0.f, 0.f};
    const float* wrow = &wl[o * 132];
#pragma unroll
    for (int k4 = 0; k4 < 32; ++k4) {
        const float4 wv = *(const float4*)&wrow[k4 * 4];
#pragma unroll
        for (int g = 0; g < 4; ++g) {
            const float4 xv = *(const float4*)&xs[(w * 4 + g) * INF + k4 * 4];
            acc[g] += wv.x * xv.x + wv.y * xv.y + wv.z * xv.z + wv.w * xv.w;
        }
    }
#pragma unroll
    for (int g = 0; g < 4; ++g) {
        int r = w * 4 + g;
        hs[r * 64 + o] = acc[g];
        hout[(row0 + r) * 64 + o] = acc[g];
    }
    __syncthreads();

    // 384 tasks: (row 0..15) x (hh 0..11) x (src/dst)
#pragma unroll
    for (int pass = 0; pass < 2; ++pass) {
        int task = t + 256 * pass;
        if (task < 384) {
            int row = task / 24;
            int rem = task - row * 24;
            int hh  = rem % 12;
            int isd = rem / 12;
            const float* hr = &hs[row * 64];
            const float* ar = &A[hh * 128 + isd * 64];
            float a = 0.f;
#pragma unroll
            for (int d4 = 0; d4 < 16; ++d4) {
                float4 hv = *(const float4*)&hr[d4 * 4];
                float4 av = *(const float4*)&ar[d4 * 4];
                a += hv.x * av.x + hv.y * av.y + hv.z * av.z + hv.w * av.w;
            }
            float* dst = isd ? edst : esrc;
            dst[(row0 + row) * 12 + hh] = a;
        }
    }
}

// ---------------- kernel 2: masked 12-head softmax + fused PV ------------
// block = (b, 16-row i-tile), 512 threads (8 waves, 2 rows per wave)
__global__ __launch_bounds__(512) void k2_attn(
    const int* __restrict__ adj, const int* __restrict__ adjin, const int* __restrict__ adjout,
    const float* __restrict__ esrc, const float* __restrict__ edst,
    const float* __restrict__ h, const float* __restrict__ ab,
    float* __restrict__ out)
{
    __shared__ float hs[NN * 64];    // 64 KB: h[b]
    __shared__ float Pl[16 * 256];   // 16 KB: summed-over-heads probabilities
    const int t = threadIdx.x;
    const int b  = blockIdx.x >> 4;
    const int i0 = (blockIdx.x & 15) * 16;

    // stage h[b] -> LDS (coalesced float4)
    {
        const float4* src = (const float4*)(h + (size_t)b * NN * 64);
        float4* dst = (float4*)hs;
#pragma unroll
        for (int i = 0; i < 8; ++i) dst[t + 512 * i] = src[t + 512 * i];
    }

    const int w = t >> 6;   // wave 0..7, owns rows 2w, 2w+1
    const int l = t & 63;   // lane: owns j = l + 64*jj, jj=0..3

    // per-lane e_dst[j][hh]
    float ed[4][12];
#pragma unroll
    for (int jj = 0; jj < 4; ++jj) {
        const float4* p = (const float4*)&edst[(size_t)(b * NN + l + 64 * jj) * 12];
        float4 v0 = p[0], v1 = p[1], v2 = p[2];
        ed[jj][0] = v0.x; ed[jj][1]  = v0.y; ed[jj][2]  = v0.z; ed[jj][3]  = v0.w;
        ed[jj][4] = v1.x; ed[jj][5]  = v1.y; ed[jj][6]  = v1.z; ed[jj][7]  = v1.w;
        ed[jj][8] = v2.x; ed[jj][9]  = v2.y; ed[jj][10] = v2.z; ed[jj][11] = v2.w;
    }

    float Pacc[2][4] = {{0.f,0.f,0.f,0.f},{0.f,0.f,0.f,0.f}};
#pragma unroll
    for (int r = 0; r < 2; ++r) {
        const int i = i0 + 2 * w + r;
        const int mbase = (b * NN + i) * NN;
        int m0[4], m1[4], m2[4];
#pragma unroll
        for (int jj = 0; jj < 4; ++jj) {
            m0[jj] = adj[mbase + l + 64 * jj];
            m1[jj] = adjin[mbase + l + 64 * jj];
            m2[jj] = adjout[mbase + l + 64 * jj];
        }
        const float* es = &esrc[(size_t)(b * NN + i) * 12];
#pragma unroll
        for (int hh = 0; hh < 12; ++hh) {
            const float e0 = es[hh] + ab[hh];
            float v[4];
#pragma unroll
            for (int jj = 0; jj < 4; ++jj) {
                float e = e0 + ed[jj][hh];
                e = e > 0.f ? e : 0.01f * e;                       // leaky_relu
                int m = (hh < 4) ? m0[jj] : (hh < 8) ? m1[jj] : m2[jj];
                v[jj] = (m > 0) ? e : NEGV;
            }
            float mx = fmaxf(fmaxf(v[0], v[1]), fmaxf(v[2], v[3]));
#pragma unroll
            for (int off = 32; off >= 1; off >>= 1)
                mx = fmaxf(mx, __shfl_xor(mx, off));
            float p[4], s = 0.f;
#pragma unroll
            for (int jj = 0; jj < 4; ++jj) {
                p[jj] = __builtin_amdgcn_exp2f((v[jj] - mx) * L2E);
                s += p[jj];
            }
#pragma unroll
            for (int off = 32; off >= 1; off >>= 1)
                s += __shfl_xor(s, off);
            const float rinv = __builtin_amdgcn_rcpf(s);
#pragma unroll
            for (int jj = 0; jj < 4; ++jj)
                Pacc[r][jj] += p[jj] * rinv;
        }
    }
#pragma unroll
    for (int r = 0; r < 2; ++r)
#pragma unroll
        for (int jj = 0; jj < 4; ++jj)
            Pl[(2 * w + r) * 256 + l + 64 * jj] = Pacc[r][jj];
    __syncthreads();

    // PV: out[i0+row][d2..d2+1] = (1/12) * sum_j P[row][j] * h[b][j][d]
    const int row = t >> 5;            // 0..15 (wave-half-uniform -> broadcast reads)
    const int d2  = (t & 31) * 2;
    const float* prow = &Pl[row * 256];
    float a0 = 0.f, a1 = 0.f;
#pragma unroll 8
    for (int j = 0; j < 256; ++j) {
        const float2 hv = *(const float2*)&hs[j * 64 + d2];
        const float pj = prow[j];
        a0 += pj * hv.x;
        a1 += pj * hv.y;
    }
    const float sc = 1.0f / 12.0f;
    float2 res; res.x = a0 * sc; res.y = a1 * sc;
    *(float2*)&out[(size_t)(b * NN + i0 + row) * 64 + d2] = res;
}

extern "C" void kernel_launch(void* const* d_in, const int* in_sizes, int n_in,
                              void* d_out, int out_size, void* d_ws, size_t ws_size,
                              hipStream_t stream) {
    const float* x    = (const float*)d_in[0];
    const int*   adj  = (const int*)d_in[1];
    const int*   adji = (const int*)d_in[2];
    const int*   adjo = (const int*)d_in[3];
    const float* W    = (const float*)d_in[4];
    const float* A    = (const float*)d_in[5];
    const float* ab   = (const float*)d_in[6];
    float* out = (float*)d_out;

    float* wsf  = (float*)d_ws;
    float* hbuf = wsf;                    // 4096*64 floats
    float* esrc = wsf + 4096 * 64;        // 4096*12
    float* edst = esrc + 4096 * 12;       // 4096*12

    k1_proj<<<256, 256, 0, stream>>>(x, W, A, hbuf, esrc, edst);
    k2_attn<<<256, 512, 0, stream>>>(adj, adji, adjo, esrc, edst, hbuf, ab, out);
}

// Round 3
// 21.929 us; speedup vs baseline: 1.3612x; 1.3612x over previous
//
#include <hip/hip_runtime.h>

#define L2E 1.44269504088896340736f

typedef __attribute__((ext_vector_type(8))) short bf16x8;
typedef __attribute__((ext_vector_type(4))) float f32x4;

// round-to-nearest-even f32 -> bf16 (returns low 16 bits)
__device__ __forceinline__ unsigned bf16_rne(float v) {
    unsigned x = __float_as_uint(v);
    return (x + 0x7FFFu + ((x >> 16) & 1u)) >> 16;
}

// ---- kernel 1: h = x@W^T (f32), write hT bf16 [b][d][j]; e_src/e_dst ----
__global__ __launch_bounds__(256) void k1_proj(
    const float* __restrict__ x, const float* __restrict__ W, const float* __restrict__ A,
    unsigned short* __restrict__ hTg, float* __restrict__ esrc, float* __restrict__ edst)
{
    __shared__ float wl[64 * 132];
    __shared__ float xs[16 * 128];
    __shared__ float hs[16 * 68];     // pitch 68: bank-spread rows
    const int t = threadIdx.x;
    const int row0 = blockIdx.x * 16;   // flat row over (B*N)
    const int b = row0 >> 8;
    const int ibase = row0 & 255;

#pragma unroll
    for (int i = 0; i < 32; ++i) {
        int idx = t + 256 * i;          // 0..8191
        wl[(idx >> 7) * 132 + (idx & 127)] = W[idx];
    }
#pragma unroll
    for (int i = 0; i < 8; ++i) {
        int idx = t + 256 * i;          // 0..2047
        xs[idx] = x[row0 * 128 + idx];
    }
    __syncthreads();

    const int o = t & 63;               // output feature
    const int w = t >> 6;               // wave id: rows w*4..w*4+3
    float acc[4] = {0.f, 0.f, 0.f, 0.f};
    const float* wrow = &wl[o * 132];
#pragma unroll
    for (int k4 = 0; k4 < 32; ++k4) {
        const float4 wv = *(const float4*)&wrow[k4 * 4];
#pragma unroll
        for (int g = 0; g < 4; ++g) {
            const float4 xv = *(const float4*)&xs[(w * 4 + g) * 128 + k4 * 4];
            acc[g] += wv.x * xv.x + wv.y * xv.y + wv.z * xv.z + wv.w * xv.w;
        }
    }
#pragma unroll
    for (int g = 0; g < 4; ++g)
        hs[(w * 4 + g) * 68 + o] = acc[g];
    __syncthreads();

    // transposed bf16 write: hTg[(b*64+d)*256 + i]
#pragma unroll
    for (int it = 0; it < 4; ++it) {
        int elem = t + 256 * it;        // 0..1023
        int d = elem >> 4, jj = elem & 15;
        hTg[(b * 64 + d) * 256 + ibase + jj] = (unsigned short)bf16_rne(hs[jj * 68 + d]);
    }

    // e_src/e_dst: 384 tasks
#pragma unroll
    for (int pass = 0; pass < 2; ++pass) {
        int task = t + 256 * pass;
        if (task < 384) {
            int row = task / 24;
            int rem = task - row * 24;
            int hh  = rem % 12;
            int isd = rem / 12;
            const float* hr = &hs[row * 68];
            const float* ar = &A[hh * 128 + isd * 64];
            float a = 0.f;
#pragma unroll
            for (int d4 = 0; d4 < 16; ++d4) {
                float4 hv = *(const float4*)&hr[d4 * 4];
                float4 av = *(const float4*)&ar[d4 * 4];
                a += hv.x * av.x + hv.y * av.y + hv.z * av.z + hv.w * av.w;
            }
            (isd ? edst : esrc)[(row0 + row) * 12 + hh] = a;
        }
    }
}

// ---- kernel 2: masked 12-head softmax (no-max) + MFMA PV ----------------
// block = (b, 8-row i-tile), 512 threads (8 waves, 1 row per wave)
__global__ __launch_bounds__(512) void k2_attn(
    const int* __restrict__ adj, const int* __restrict__ adjin, const int* __restrict__ adjout,
    const float* __restrict__ esrc, const float* __restrict__ edst,
    const unsigned short* __restrict__ hTg, const float* __restrict__ ab,
    float* __restrict__ out)
{
    __shared__ unsigned short hT[64 * 264];   // bf16 h^T [d][j], pitch 264 (33.0 KB)
    __shared__ float edl[12 * 256];           // e_dst^T [hh][j] (12 KB); reused as red[]
    __shared__ unsigned short Ph[16 * 264];   // P hi bf16 [row][j] (8.25 KB)
    __shared__ unsigned short Pl_[16 * 264];  // P lo bf16

    const int t = threadIdx.x;
    const int b  = blockIdx.x >> 5;
    const int i0 = (blockIdx.x & 31) * 8;
    const int lane = t & 63;
    const int w = t >> 6;

    // stage hT (coalesced uint4 = 8 bf16)
    {
        const uint4* src = (const uint4*)(hTg + (size_t)b * 64 * 256);
#pragma unroll
        for (int it = 0; it < 4; ++it) {
            int task = t + 512 * it;          // 0..2047
            int d = task >> 5, jg = task & 31;
            *(uint4*)&hT[d * 264 + jg * 8] = src[d * 32 + jg];
        }
    }
    // stage edl transposed
    {
        const float* eb = edst + (size_t)b * 256 * 12;
#pragma unroll
        for (int e = 0; e < 6; ++e) {
            int elem = t + 512 * e;           // 0..3071
            int j = elem / 12;
            int hh = elem - j * 12;
            edl[hh * 256 + j] = eb[elem];
        }
    }
    __syncthreads();

    // ---- softmax: wave w owns row i0+w; lane owns j = 4*lane..4*lane+3 ----
    const int gi = b * 256 + i0 + w;
    const int4 M0 = *(const int4*)(adj    + (size_t)gi * 256 + 4 * lane);
    const int4 M1 = *(const int4*)(adjin  + (size_t)gi * 256 + 4 * lane);
    const int4 M2 = *(const int4*)(adjout + (size_t)gi * 256 + 4 * lane);
    const float mA[4] = {(float)M0.x, (float)M0.y, (float)M0.z, (float)M0.w};
    const float mB[4] = {(float)M1.x, (float)M1.y, (float)M1.z, (float)M1.w};
    const float mC[4] = {(float)M2.x, (float)M2.y, (float)M2.z, (float)M2.w};

    const float* es = esrc + (size_t)gi * 12;
    float Pacc[4] = {0.f, 0.f, 0.f, 0.f};
#pragma unroll
    for (int hh = 0; hh < 12; ++hh) {
        const float e0 = es[hh] + ab[hh];
        const float4 ev = *(const float4*)&edl[hh * 256 + 4 * lane];
        float v0 = e0 + ev.x, v1 = e0 + ev.y, v2 = e0 + ev.z, v3 = e0 + ev.w;
        v0 = v0 > 0.f ? v0 : 0.01f * v0;
        v1 = v1 > 0.f ? v1 : 0.01f * v1;
        v2 = v2 > 0.f ? v2 : 0.01f * v2;
        v3 = v3 > 0.f ? v3 : 0.01f * v3;
        const float m0 = (hh < 4) ? mA[0] : (hh < 8) ? mB[0] : mC[0];
        const float m1 = (hh < 4) ? mA[1] : (hh < 8) ? mB[1] : mC[1];
        const float m2 = (hh < 4) ? mA[2] : (hh < 8) ? mB[2] : mC[2];
        const float m3 = (hh < 4) ? mA[3] : (hh < 8) ? mB[3] : mC[3];
        float p0 = __builtin_amdgcn_exp2f(v0 * L2E) * m0;
        float p1 = __builtin_amdgcn_exp2f(v1 * L2E) * m1;
        float p2 = __builtin_amdgcn_exp2f(v2 * L2E) * m2;
        float p3 = __builtin_amdgcn_exp2f(v3 * L2E) * m3;
        float s = (p0 + p1) + (p2 + p3);
#pragma unroll
        for (int off = 32; off >= 1; off >>= 1)
            s += __shfl_xor(s, off);
        const float rinv = __builtin_amdgcn_rcpf(s);
        Pacc[0] += p0 * rinv;
        Pacc[1] += p1 * rinv;
        Pacc[2] += p2 * rinv;
        Pacc[3] += p3 * rinv;
    }
    // write P hi/lo bf16
    {
        unsigned h0 = bf16_rne(Pacc[0]);
        unsigned h1 = bf16_rne(Pacc[1]);
        unsigned h2 = bf16_rne(Pacc[2]);
        unsigned h3 = bf16_rne(Pacc[3]);
        unsigned l0 = bf16_rne(Pacc[0] - __uint_as_float(h0 << 16));
        unsigned l1 = bf16_rne(Pacc[1] - __uint_as_float(h1 << 16));
        unsigned l2 = bf16_rne(Pacc[2] - __uint_as_float(h2 << 16));
        unsigned l3 = bf16_rne(Pacc[3] - __uint_as_float(h3 << 16));
        uint2 hw; hw.x = h0 | (h1 << 16); hw.y = h2 | (h3 << 16);
        uint2 lw; lw.x = l0 | (l1 << 16); lw.y = l2 | (l3 << 16);
        *(uint2*)&Ph[w * 264 + 4 * lane]  = hw;
        *(uint2*)&Pl_[w * 264 + 4 * lane] = lw;
    }
    __syncthreads();

    // ---- PV via MFMA: out[8][64] = P[8][256] x h[256][64] ----
    // wave (nt = w&3 -> 16-d slice, kh = w>>2 -> K half)
    const int nt = w & 3, kh = w >> 2;
    const int ml = lane & 15, kb = lane >> 4;
    f32x4 acc = {0.f, 0.f, 0.f, 0.f};
#pragma unroll
    for (int ks = 0; ks < 4; ++ks) {
        const int koff = kh * 128 + ks * 32 + kb * 8;
        bf16x8 ah = *(const bf16x8*)&Ph[ml * 264 + koff];
        bf16x8 al = *(const bf16x8*)&Pl_[ml * 264 + koff];
        bf16x8 bh = *(const bf16x8*)&hT[(nt * 16 + ml) * 264 + koff];
        acc = __builtin_amdgcn_mfma_f32_16x16x32_bf16(ah, bh, acc, 0, 0, 0);
        acc = __builtin_amdgcn_mfma_f32_16x16x32_bf16(al, bh, acc, 0, 0, 0);
    }

    float* red = edl;   // overlay (edl dead after softmax barrier)
    if (kh == 1 && lane < 32) {
#pragma unroll
        for (int r = 0; r < 4; ++r)
            red[nt * 144 + ml * 9 + kb * 4 + r] = acc[r];
    }
    __syncthreads();
    if (kh == 0 && lane < 32) {
#pragma unroll
        for (int r = 0; r < 4; ++r) {
            const int mrow = kb * 4 + r;
            const float v = (acc[r] + red[nt * 144 + ml * 9 + mrow]) * (1.0f / 12.0f);
            out[(size_t)(b * 256 + i0 + mrow) * 64 + nt * 16 + ml] = v;
        }
    }
}

extern "C" void kernel_launch(void* const* d_in, const int* in_sizes, int n_in,
                              void* d_out, int out_size, void* d_ws, size_t ws_size,
                              hipStream_t stream) {
    const float* x    = (const float*)d_in[0];
    const int*   adj  = (const int*)d_in[1];
    const int*   adji = (const int*)d_in[2];
    const int*   adjo = (const int*)d_in[3];
    const float* W    = (const float*)d_in[4];
    const float* A    = (const float*)d_in[5];
    const float* ab   = (const float*)d_in[6];
    float* out = (float*)d_out;

    unsigned short* hTg = (unsigned short*)d_ws;            // 4096*64 bf16 = 512 KB
    float* esrc = (float*)((char*)d_ws + (1 << 20));        // 4096*12 f32
    float* edst = esrc + 4096 * 12;                         // 4096*12 f32

    k1_proj<<<256, 256, 0, stream>>>(x, W, A, hTg, esrc, edst);
    k2_attn<<<512, 512, 0, stream>>>(adj, adji, adjo, esrc, edst, hTg, ab, out);
}

// Round 4
// 19.735 us; speedup vs baseline: 1.5125x; 1.1112x over previous
//
#include <hip/hip_runtime.h>

#define L2E 1.44269504088896340736f

typedef __attribute__((ext_vector_type(8))) short bf16x8;
typedef __attribute__((ext_vector_type(4))) float f32x4;

__device__ __forceinline__ unsigned bf16_rne(float v) {
    unsigned x = __float_as_uint(v);
    return (x + 0x7FFFu + ((x >> 16) & 1u)) >> 16;
}

// float4 -> bf16 hi (uint2 = 4 packed) and lo residual (uint2)
__device__ __forceinline__ void cvt_hilo4(float4 v, uint2* hi, uint2* lo) {
    unsigned h0 = bf16_rne(v.x), h1 = bf16_rne(v.y), h2 = bf16_rne(v.z), h3 = bf16_rne(v.w);
    float f0 = __uint_as_float(h0 << 16), f1 = __uint_as_float(h1 << 16);
    float f2 = __uint_as_float(h2 << 16), f3 = __uint_as_float(h3 << 16);
    unsigned l0 = bf16_rne(v.x - f0), l1 = bf16_rne(v.y - f1);
    unsigned l2 = bf16_rne(v.z - f2), l3 = bf16_rne(v.w - f3);
    hi->x = h0 | (h1 << 16); hi->y = h2 | (h3 << 16);
    lo->x = l0 | (l1 << 16); lo->y = l2 | (l3 << 16);
}

// ---- kernel 1 (all-MFMA): h = x@W^T ; [esrc|edstT] = h@[A1;A2]^T ; hT bf16 ----
// 256 blocks x 256 thr, 16 rows each. bf16 hi/lo 3-term => ~f32 precision.
__global__ __launch_bounds__(256) void k1_proj(
    const float* __restrict__ x, const float* __restrict__ W, const float* __restrict__ A,
    unsigned short* __restrict__ hTg, float* __restrict__ esrc, float* __restrict__ edstT)
{
    __shared__ unsigned short xh[16 * 136], xl[16 * 136];
    __shared__ unsigned short wh[64 * 136], wl[64 * 136];
    __shared__ unsigned short Ach[32 * 72], Acl[32 * 72];
    __shared__ unsigned short hsh[16 * 72], hsl[16 * 72];

    const int t = threadIdx.x;
    const int row0 = blockIdx.x * 16;
    const int b = row0 >> 8;
    const int ibase = row0 & 255;

    // stage+convert x tile (16x128)
#pragma unroll
    for (int p = 0; p < 2; ++p) {
        int q = t + 256 * p;                 // float4 group 0..511
        int r = q >> 5, c = (q & 31) * 4;
        float4 v = *(const float4*)&x[row0 * 128 + 4 * q];
        uint2 hi, lo; cvt_hilo4(v, &hi, &lo);
        *(uint2*)&xh[r * 136 + c] = hi;
        *(uint2*)&xl[r * 136 + c] = lo;
    }
    // stage+convert W (64x128)
#pragma unroll
    for (int p = 0; p < 8; ++p) {
        int q = t + 256 * p;                 // 0..2047
        int r = q >> 5, c = (q & 31) * 4;
        float4 v = *(const float4*)&W[4 * q];
        uint2 hi, lo; cvt_hilo4(v, &hi, &lo);
        *(uint2*)&wh[r * 136 + c] = hi;
        *(uint2*)&wl[r * 136 + c] = lo;
    }
    // stage+convert Acat = [A1;A2] (24x64, zero-pad to 32 rows)
#pragma unroll
    for (int p = 0; p < 2; ++p) {
        int q = t + 256 * p;                 // 0..511
        int n = q >> 4, d = (q & 15) * 4;
        float4 v = make_float4(0.f, 0.f, 0.f, 0.f);
        if (n < 24) {
            int nn = (n < 12) ? n : n - 12;
            v = *(const float4*)&A[nn * 128 + ((n < 12) ? 0 : 64) + d];
        }
        uint2 hi, lo; cvt_hilo4(v, &hi, &lo);
        *(uint2*)&Ach[n * 72 + d] = hi;
        *(uint2*)&Acl[n * 72 + d] = lo;
    }
    __syncthreads();

    const int lane = t & 63;
    const int wv = t >> 6;                   // wave 0..3 -> 16-col slice of h
    const int ml = lane & 15, kb = lane >> 4;

    // h-MFMA: h[16][64], K=128
    f32x4 acc = {0.f, 0.f, 0.f, 0.f};
#pragma unroll
    for (int ks = 0; ks < 4; ++ks) {
        const int ko = ks * 32 + kb * 8;
        bf16x8 axh = *(const bf16x8*)&xh[ml * 136 + ko];
        bf16x8 axl = *(const bf16x8*)&xl[ml * 136 + ko];
        bf16x8 bwh = *(const bf16x8*)&wh[(wv * 16 + ml) * 136 + ko];
        bf16x8 bwl = *(const bf16x8*)&wl[(wv * 16 + ml) * 136 + ko];
        acc = __builtin_amdgcn_mfma_f32_16x16x32_bf16(axh, bwh, acc, 0, 0, 0);
        acc = __builtin_amdgcn_mfma_f32_16x16x32_bf16(axh, bwl, acc, 0, 0, 0);
        acc = __builtin_amdgcn_mfma_f32_16x16x32_bf16(axl, bwh, acc, 0, 0, 0);
    }
    // store h hi/lo to LDS (row m = kb*4+r, col = wv*16+ml)
#pragma unroll
    for (int r = 0; r < 4; ++r) {
        const int m = kb * 4 + r, c = wv * 16 + ml;
        unsigned hi = bf16_rne(acc[r]);
        float hif = __uint_as_float(hi << 16);
        hsh[m * 72 + c] = (unsigned short)hi;
        hsl[m * 72 + c] = (unsigned short)bf16_rne(acc[r] - hif);
    }
    __syncthreads();

    // e-MFMA: e[16][24] = h[16][64] @ Acat[24][64]^T (waves 0,1)
    if (wv < 2) {
        f32x4 e4 = {0.f, 0.f, 0.f, 0.f};
#pragma unroll
        for (int ks = 0; ks < 2; ++ks) {
            const int ko = ks * 32 + kb * 8;
            bf16x8 ah = *(const bf16x8*)&hsh[ml * 72 + ko];
            bf16x8 al = *(const bf16x8*)&hsl[ml * 72 + ko];
            bf16x8 bh = *(const bf16x8*)&Ach[(wv * 16 + ml) * 72 + ko];
            bf16x8 bl = *(const bf16x8*)&Acl[(wv * 16 + ml) * 72 + ko];
            e4 = __builtin_amdgcn_mfma_f32_16x16x32_bf16(ah, bh, e4, 0, 0, 0);
            e4 = __builtin_amdgcn_mfma_f32_16x16x32_bf16(ah, bl, e4, 0, 0, 0);
            e4 = __builtin_amdgcn_mfma_f32_16x16x32_bf16(al, bh, e4, 0, 0, 0);
        }
#pragma unroll
        for (int r = 0; r < 4; ++r) {
            const int m = kb * 4 + r, n = wv * 16 + ml;
            if (n < 12)
                esrc[(row0 + m) * 12 + n] = e4[r];
            else if (n < 24)
                edstT[(b * 12 + (n - 12)) * 256 + ibase + m] = e4[r];
        }
    }

    // hT write: hTg[(b*64+d)*256 + i] (bf16 hi)
#pragma unroll
    for (int it = 0; it < 4; ++it) {
        int e2 = t + 256 * it;               // 0..1023
        int d = e2 >> 4, jj = e2 & 15;
        hTg[(b * 64 + d) * 256 + ibase + jj] = hsh[jj * 72 + d];
    }
}

// ---- kernel 2: masked 12-head softmax (no-max) + MFMA PV, B from L2 ----
// 1024 blocks x 256 thr (4 waves); wave = 1 row; 16 waves/CU.
__global__ __launch_bounds__(256) void k2_attn(
    const int* __restrict__ adj, const int* __restrict__ adjin, const int* __restrict__ adjout,
    const float* __restrict__ esrc, const float* __restrict__ edstT,
    const unsigned short* __restrict__ hTg, const float* __restrict__ ab,
    float* __restrict__ out)
{
    __shared__ unsigned short Ph[16 * 264];   // P hi bf16 (rows 0..3 valid)
    __shared__ unsigned short Pl_[16 * 264];  // P lo bf16

    const int t = threadIdx.x;
    const int b  = blockIdx.x >> 6;
    const int i0 = (blockIdx.x & 63) * 4;
    const int lane = t & 63;
    const int wv = t >> 6;                    // wave 0..3 -> row i0+wv
    const int gi = b * 256 + i0 + wv;

    // masks (coalesced int4: lane owns j = 4*lane..4*lane+3)
    const int4 M0 = *(const int4*)(adj    + (size_t)gi * 256 + 4 * lane);
    const int4 M1 = *(const int4*)(adjin  + (size_t)gi * 256 + 4 * lane);
    const int4 M2 = *(const int4*)(adjout + (size_t)gi * 256 + 4 * lane);
    const float mA[4] = {(float)M0.x, (float)M0.y, (float)M0.z, (float)M0.w};
    const float mB[4] = {(float)M1.x, (float)M1.y, (float)M1.z, (float)M1.w};
    const float mC[4] = {(float)M2.x, (float)M2.y, (float)M2.z, (float)M2.w};

    // hoisted e0[hh] = esrc + bias
    const float* es = esrc + (size_t)gi * 12;
    float e0[12];
#pragma unroll
    for (int hh = 0; hh < 12; ++hh) e0[hh] = es[hh] + ab[hh];

    float Pacc[4] = {0.f, 0.f, 0.f, 0.f};
#pragma unroll
    for (int hh = 0; hh < 12; ++hh) {
        const float4 ev = *(const float4*)&edstT[(size_t)(b * 12 + hh) * 256 + 4 * lane];
        float v0 = e0[hh] + ev.x, v1 = e0[hh] + ev.y, v2 = e0[hh] + ev.z, v3 = e0[hh] + ev.w;
        v0 = v0 > 0.f ? v0 : 0.01f * v0;
        v1 = v1 > 0.f ? v1 : 0.01f * v1;
        v2 = v2 > 0.f ? v2 : 0.01f * v2;
        v3 = v3 > 0.f ? v3 : 0.01f * v3;
        const float m0 = (hh < 4) ? mA[0] : (hh < 8) ? mB[0] : mC[0];
        const float m1 = (hh < 4) ? mA[1] : (hh < 8) ? mB[1] : mC[1];
        const float m2 = (hh < 4) ? mA[2] : (hh < 8) ? mB[2] : mC[2];
        const float m3 = (hh < 4) ? mA[3] : (hh < 8) ? mB[3] : mC[3];
        float p0 = __builtin_amdgcn_exp2f(v0 * L2E) * m0;
        float p1 = __builtin_amdgcn_exp2f(v1 * L2E) * m1;
        float p2 = __builtin_amdgcn_exp2f(v2 * L2E) * m2;
        float p3 = __builtin_amdgcn_exp2f(v3 * L2E) * m3;
        float s = (p0 + p1) + (p2 + p3);
#pragma unroll
        for (int off = 32; off >= 1; off >>= 1)
            s += __shfl_xor(s, off);
        const float rinv = __builtin_amdgcn_rcpf(s);
        Pacc[0] += p0 * rinv;
        Pacc[1] += p1 * rinv;
        Pacc[2] += p2 * rinv;
        Pacc[3] += p3 * rinv;
    }
    // P -> bf16 hi/lo in LDS (row wv)
    {
        unsigned h0 = bf16_rne(Pacc[0]), h1 = bf16_rne(Pacc[1]);
        unsigned h2 = bf16_rne(Pacc[2]), h3 = bf16_rne(Pacc[3]);
        unsigned l0 = bf16_rne(Pacc[0] - __uint_as_float(h0 << 16));
        unsigned l1 = bf16_rne(Pacc[1] - __uint_as_float(h1 << 16));
        unsigned l2 = bf16_rne(Pacc[2] - __uint_as_float(h2 << 16));
        unsigned l3 = bf16_rne(Pacc[3] - __uint_as_float(h3 << 16));
        uint2 hw; hw.x = h0 | (h1 << 16); hw.y = h2 | (h3 << 16);
        uint2 lw; lw.x = l0 | (l1 << 16); lw.y = l2 | (l3 << 16);
        *(uint2*)&Ph[wv * 264 + 4 * lane]  = hw;
        *(uint2*)&Pl_[wv * 264 + 4 * lane] = lw;
    }
    __syncthreads();

    // PV: out[4][64] = P[4][256] x hT[64][256]^T ; B-frags straight from L2
    const int ml = lane & 15, kb = lane >> 4;
    const unsigned short* hTb = hTg + ((size_t)b * 64 + wv * 16 + ml) * 256;
    f32x4 acc = {0.f, 0.f, 0.f, 0.f};
#pragma unroll
    for (int ks = 0; ks < 8; ++ks) {
        const int ko = ks * 32 + kb * 8;
        bf16x8 bh = *(const bf16x8*)&hTb[ko];
        bf16x8 ah = *(const bf16x8*)&Ph[ml * 264 + ko];
        bf16x8 al = *(const bf16x8*)&Pl_[ml * 264 + ko];
        acc = __builtin_amdgcn_mfma_f32_16x16x32_bf16(ah, bh, acc, 0, 0, 0);
        acc = __builtin_amdgcn_mfma_f32_16x16x32_bf16(al, bh, acc, 0, 0, 0);
    }
    if (kb == 0) {
#pragma unroll
        for (int r = 0; r < 4; ++r)
            out[(size_t)(b * 256 + i0 + r) * 64 + wv * 16 + ml] = acc[r] * (1.0f / 12.0f);
    }
}

extern "C" void kernel_launch(void* const* d_in, const int* in_sizes, int n_in,
                              void* d_out, int out_size, void* d_ws, size_t ws_size,
                              hipStream_t stream) {
    const float* x    = (const float*)d_in[0];
    const int*   adj  = (const int*)d_in[1];
    const int*   adji = (const int*)d_in[2];
    const int*   adjo = (const int*)d_in[3];
    const float* W    = (const float*)d_in[4];
    const float* A    = (const float*)d_in[5];
    const float* ab   = (const float*)d_in[6];
    float* out = (float*)d_out;

    unsigned short* hTg = (unsigned short*)d_ws;              // 4096*64 bf16 = 512 KB
    float* esrc  = (float*)((char*)d_ws + (512 << 10));       // 4096*12 f32 = 192 KB
    float* edstT = (float*)((char*)d_ws + (704 << 10));       // 16*12*256 f32 = 192 KB

    k1_proj<<<256, 256, 0, stream>>>(x, W, A, hTg, esrc, edstT);
    k2_attn<<<1024, 256, 0, stream>>>(adj, adji, adjo, esrc, edstT, hTg, ab, out);
}

// Round 5
// 18.002 us; speedup vs baseline: 1.6581x; 1.0963x over previous
//
#include <hip/hip_runtime.h>

#define L2E 1.44269504088896340736f

typedef __attribute__((ext_vector_type(8))) short bf16x8;
typedef __attribute__((ext_vector_type(4))) float f32x4;

__device__ __forceinline__ unsigned bf16_rne(float v) {
    unsigned x = __float_as_uint(v);
    return (x + 0x7FFFu + ((x >> 16) & 1u)) >> 16;
}

__device__ __forceinline__ void cvt_hilo4(float4 v, uint2* hi, uint2* lo) {
    unsigned h0 = bf16_rne(v.x), h1 = bf16_rne(v.y), h2 = bf16_rne(v.z), h3 = bf16_rne(v.w);
    float f0 = __uint_as_float(h0 << 16), f1 = __uint_as_float(h1 << 16);
    float f2 = __uint_as_float(h2 << 16), f3 = __uint_as_float(h3 << 16);
    unsigned l0 = bf16_rne(v.x - f0), l1 = bf16_rne(v.y - f1);
    unsigned l2 = bf16_rne(v.z - f2), l3 = bf16_rne(v.w - f3);
    hi->x = h0 | (h1 << 16); hi->y = h2 | (h3 << 16);
    lo->x = l0 | (l1 << 16); lo->y = l2 | (l3 << 16);
}

// ---- kernel 1 (all-MFMA): h = x@W^T ; esrc'=(h@A1^T+ab)*L2E ; edstT'=(h@A2^T)*L2E ; hT bf16 ----
__global__ __launch_bounds__(256) void k1_proj(
    const float* __restrict__ x, const float* __restrict__ W, const float* __restrict__ A,
    const float* __restrict__ ab,
    unsigned short* __restrict__ hTg, float* __restrict__ esrc, float* __restrict__ edstT)
{
    __shared__ unsigned short xh[16 * 136], xl[16 * 136];
    __shared__ unsigned short wh[64 * 136], wl[64 * 136];
    __shared__ unsigned short Ach[32 * 72], Acl[32 * 72];
    __shared__ unsigned short hsh[16 * 72], hsl[16 * 72];

    const int t = threadIdx.x;
    const int row0 = blockIdx.x * 16;
    const int b = row0 >> 8;
    const int ibase = row0 & 255;

#pragma unroll
    for (int p = 0; p < 2; ++p) {
        int q = t + 256 * p;
        int r = q >> 5, c = (q & 31) * 4;
        float4 v = *(const float4*)&x[row0 * 128 + 4 * q];
        uint2 hi, lo; cvt_hilo4(v, &hi, &lo);
        *(uint2*)&xh[r * 136 + c] = hi;
        *(uint2*)&xl[r * 136 + c] = lo;
    }
#pragma unroll
    for (int p = 0; p < 8; ++p) {
        int q = t + 256 * p;
        int r = q >> 5, c = (q & 31) * 4;
        float4 v = *(const float4*)&W[4 * q];
        uint2 hi, lo; cvt_hilo4(v, &hi, &lo);
        *(uint2*)&wh[r * 136 + c] = hi;
        *(uint2*)&wl[r * 136 + c] = lo;
    }
#pragma unroll
    for (int p = 0; p < 2; ++p) {
        int q = t + 256 * p;
        int n = q >> 4, d = (q & 15) * 4;
        float4 v = make_float4(0.f, 0.f, 0.f, 0.f);
        if (n < 24) {
            int nn = (n < 12) ? n : n - 12;
            v = *(const float4*)&A[nn * 128 + ((n < 12) ? 0 : 64) + d];
        }
        uint2 hi, lo; cvt_hilo4(v, &hi, &lo);
        *(uint2*)&Ach[n * 72 + d] = hi;
        *(uint2*)&Acl[n * 72 + d] = lo;
    }
    __syncthreads();

    const int lane = t & 63;
    const int wv = t >> 6;
    const int ml = lane & 15, kb = lane >> 4;

    f32x4 acc = {0.f, 0.f, 0.f, 0.f};
#pragma unroll
    for (int ks = 0; ks < 4; ++ks) {
        const int ko = ks * 32 + kb * 8;
        bf16x8 axh = *(const bf16x8*)&xh[ml * 136 + ko];
        bf16x8 axl = *(const bf16x8*)&xl[ml * 136 + ko];
        bf16x8 bwh = *(const bf16x8*)&wh[(wv * 16 + ml) * 136 + ko];
        bf16x8 bwl = *(const bf16x8*)&wl[(wv * 16 + ml) * 136 + ko];
        acc = __builtin_amdgcn_mfma_f32_16x16x32_bf16(axh, bwh, acc, 0, 0, 0);
        acc = __builtin_amdgcn_mfma_f32_16x16x32_bf16(axh, bwl, acc, 0, 0, 0);
        acc = __builtin_amdgcn_mfma_f32_16x16x32_bf16(axl, bwh, acc, 0, 0, 0);
    }
#pragma unroll
    for (int r = 0; r < 4; ++r) {
        const int m = kb * 4 + r, c = wv * 16 + ml;
        unsigned hi = bf16_rne(acc[r]);
        float hif = __uint_as_float(hi << 16);
        hsh[m * 72 + c] = (unsigned short)hi;
        hsl[m * 72 + c] = (unsigned short)bf16_rne(acc[r] - hif);
    }
    __syncthreads();

    // e-MFMA: e[16][24] = h[16][64] @ Acat[24][64]^T (waves 0,1)
    if (wv < 2) {
        f32x4 e4 = {0.f, 0.f, 0.f, 0.f};
#pragma unroll
        for (int ks = 0; ks < 2; ++ks) {
            const int ko = ks * 32 + kb * 8;
            bf16x8 ah = *(const bf16x8*)&hsh[ml * 72 + ko];
            bf16x8 al = *(const bf16x8*)&hsl[ml * 72 + ko];
            bf16x8 bh = *(const bf16x8*)&Ach[(wv * 16 + ml) * 72 + ko];
            bf16x8 bl = *(const bf16x8*)&Acl[(wv * 16 + ml) * 72 + ko];
            e4 = __builtin_amdgcn_mfma_f32_16x16x32_bf16(ah, bh, e4, 0, 0, 0);
            e4 = __builtin_amdgcn_mfma_f32_16x16x32_bf16(ah, bl, e4, 0, 0, 0);
            e4 = __builtin_amdgcn_mfma_f32_16x16x32_bf16(al, bh, e4, 0, 0, 0);
        }
#pragma unroll
        for (int r = 0; r < 4; ++r) {
            const int m = kb * 4 + r, n = wv * 16 + ml;
            if (n < 12)
                esrc[(row0 + m) * 12 + n] = (e4[r] + ab[n]) * L2E;   // pre-bias + pre-scale
            else if (n < 24)
                edstT[(b * 12 + (n - 12)) * 256 + ibase + m] = e4[r] * L2E;
        }
    }

    // hT write packed (uint = 2 bf16): hTg[(b*64+d)*256 + i]
#pragma unroll
    for (int it = 0; it < 2; ++it) {
        int e2 = t + 256 * it;               // 0..511
        int d = e2 >> 3, j2 = (e2 & 7) * 2;
        unsigned lo16 = hsh[j2 * 72 + d], hi16 = hsh[(j2 + 1) * 72 + d];
        *(unsigned*)&hTg[(b * 64 + d) * 256 + ibase + j2] = lo16 | (hi16 << 16);
    }
}

// ---- kernel 2: masked 12-head softmax (no-max, pre-scaled) + MFMA PV ----
// 512 blocks x 256 thr (4 waves); wave = 2 rows (32-lane groups); block = 8 rows.
__global__ __launch_bounds__(256) void k2_attn(
    const int* __restrict__ adj, const int* __restrict__ adjin, const int* __restrict__ adjout,
    const float* __restrict__ esrc, const float* __restrict__ edstT,
    const unsigned short* __restrict__ hTg,
    float* __restrict__ out)
{
    __shared__ unsigned short Ph[16 * 264];   // rows 0..7 = P bf16; rows 8..15 zeroed

    const int t = threadIdx.x;
    const int b  = blockIdx.x >> 5;
    const int i0 = (blockIdx.x & 31) * 8;
    const int lane = t & 63;
    const int wv = t >> 6;                    // 0..3
    const int g = lane >> 5;                  // half-wave -> row parity
    const int q = lane & 31;                  // j-block: j = 8q..8q+7
    const int row = wv * 2 + g;               // 0..7
    const int gi = b * 256 + i0 + row;

    // zero Ph rows 8..15 (MFMA A-fragment reads them)
    {
        uint4* z = (uint4*)&Ph[8 * 264];
        if (t < 264) z[t] = make_uint4(0, 0, 0, 0);
    }

    // masks: 8 j per lane, 2 int4 per type
    const int4* mp0 = (const int4*)(adj    + (size_t)gi * 256 + 8 * q);
    const int4* mp1 = (const int4*)(adjin  + (size_t)gi * 256 + 8 * q);
    const int4* mp2 = (const int4*)(adjout + (size_t)gi * 256 + 8 * q);
    int4 Ma0 = mp0[0], Ma1 = mp0[1];
    int4 Mb0 = mp1[0], Mb1 = mp1[1];
    int4 Mc0 = mp2[0], Mc1 = mp2[1];
    float fm[3][8];
    fm[0][0] = (float)Ma0.x; fm[0][1] = (float)Ma0.y; fm[0][2] = (float)Ma0.z; fm[0][3] = (float)Ma0.w;
    fm[0][4] = (float)Ma1.x; fm[0][5] = (float)Ma1.y; fm[0][6] = (float)Ma1.z; fm[0][7] = (float)Ma1.w;
    fm[1][0] = (float)Mb0.x; fm[1][1] = (float)Mb0.y; fm[1][2] = (float)Mb0.z; fm[1][3] = (float)Mb0.w;
    fm[1][4] = (float)Mb1.x; fm[1][5] = (float)Mb1.y; fm[1][6] = (float)Mb1.z; fm[1][7] = (float)Mb1.w;
    fm[2][0] = (float)Mc0.x; fm[2][1] = (float)Mc0.y; fm[2][2] = (float)Mc0.z; fm[2][3] = (float)Mc0.w;
    fm[2][4] = (float)Mc1.x; fm[2][5] = (float)Mc1.y; fm[2][6] = (float)Mc1.z; fm[2][7] = (float)Mc1.w;

    // e0 (pre-biased, pre-scaled by L2E in k1)
    const float4* ep = (const float4*)(esrc + (size_t)gi * 12);
    const float4 eA = ep[0], eB = ep[1], eC = ep[2];
    const float e0[12] = {eA.x, eA.y, eA.z, eA.w, eB.x, eB.y, eB.z, eB.w, eC.x, eC.y, eC.z, eC.w};

    float Pacc[8] = {0.f, 0.f, 0.f, 0.f, 0.f, 0.f, 0.f, 0.f};
#pragma unroll
    for (int hh = 0; hh < 12; ++hh) {
        const int grp = hh >> 2;
        const float4* evp = (const float4*)(edstT + (size_t)(b * 12 + hh) * 256 + 8 * q);
        const float4 ev0 = evp[0], ev1 = evp[1];
        const float evv[8] = {ev0.x, ev0.y, ev0.z, ev0.w, ev1.x, ev1.y, ev1.z, ev1.w};
        float p[8], s = 0.f;
#pragma unroll
        for (int k = 0; k < 8; ++k) {
            float v = e0[hh] + evv[k];
            v = fmaxf(v, 0.01f * v);                       // leaky in log2 domain
            p[k] = __builtin_amdgcn_exp2f(v) * fm[grp][k];
            s += p[k];
        }
#pragma unroll
        for (int off = 16; off >= 1; off >>= 1)
            s += __shfl_xor(s, off);                       // 32-lane group reduce
        const float rinv = __builtin_amdgcn_rcpf(s);
#pragma unroll
        for (int k = 0; k < 8; ++k)
            Pacc[k] += p[k] * rinv;
    }
    // P -> bf16 hi only, packed uint4 (8 values)
    {
        uint4 pk;
        pk.x = bf16_rne(Pacc[0]) | (bf16_rne(Pacc[1]) << 16);
        pk.y = bf16_rne(Pacc[2]) | (bf16_rne(Pacc[3]) << 16);
        pk.z = bf16_rne(Pacc[4]) | (bf16_rne(Pacc[5]) << 16);
        pk.w = bf16_rne(Pacc[6]) | (bf16_rne(Pacc[7]) << 16);
        *(uint4*)&Ph[row * 264 + 8 * q] = pk;
    }
    __syncthreads();

    // PV: out[8][64] = P[8][256] x hT^T ; B-frags from L2; wave -> 16-d slice
    const int ml = lane & 15, kb = lane >> 4;
    const unsigned short* hTb = hTg + ((size_t)b * 64 + wv * 16 + ml) * 256;
    f32x4 acc = {0.f, 0.f, 0.f, 0.f};
#pragma unroll
    for (int ks = 0; ks < 8; ++ks) {
        const int ko = ks * 32 + kb * 8;
        bf16x8 bh = *(const bf16x8*)&hTb[ko];
        bf16x8 ah = *(const bf16x8*)&Ph[ml * 264 + ko];
        acc = __builtin_amdgcn_mfma_f32_16x16x32_bf16(ah, bh, acc, 0, 0, 0);
    }
    if (kb < 2) {
#pragma unroll
        for (int r = 0; r < 4; ++r) {
            const int m = kb * 4 + r;     // 0..7
            out[(size_t)(b * 256 + i0 + m) * 64 + wv * 16 + ml] = acc[r] * (1.0f / 12.0f);
        }
    }
}

extern "C" void kernel_launch(void* const* d_in, const int* in_sizes, int n_in,
                              void* d_out, int out_size, void* d_ws, size_t ws_size,
                              hipStream_t stream) {
    const float* x    = (const float*)d_in[0];
    const int*   adj  = (const int*)d_in[1];
    const int*   adji = (const int*)d_in[2];
    const int*   adjo = (const int*)d_in[3];
    const float* W    = (const float*)d_in[4];
    const float* A    = (const float*)d_in[5];
    const float* ab   = (const float*)d_in[6];
    float* out = (float*)d_out;

    unsigned short* hTg = (unsigned short*)d_ws;              // 512 KB
    float* esrc  = (float*)((char*)d_ws + (512 << 10));       // 192 KB
    float* edstT = (float*)((char*)d_ws + (704 << 10));       // 192 KB

    k1_proj<<<256, 256, 0, stream>>>(x, W, A, ab, hTg, esrc, edstT);
    k2_attn<<<512, 256, 0, stream>>>(adj, adji, adjo, esrc, edstT, hTg, out);
}